// Round 11
// baseline (225.513 us; speedup 1.0000x reference)
//
#include <hip/hip_runtime.h>
#include <math.h>

#define EPSILON 0.3f
#define ALPHA 0.7f
#define LN_EPS 1e-5f

typedef __bf16 bf16x8 __attribute__((ext_vector_type(8)));
typedef float f32x4 __attribute__((ext_vector_type(4)));

__device__ __forceinline__ unsigned short f2bf(float f) {
  unsigned int u = __float_as_uint(f);
  return (unsigned short)((u + 0x7fffu + ((u >> 16) & 1u)) >> 16);
}
__device__ __forceinline__ unsigned int pack2(float lo, float hi) {
  return (unsigned int)f2bf(lo) | ((unsigned int)f2bf(hi) << 16);
}

// async 16B/lane global->LDS DMA; lds base wave-uniform (HW adds lane*16)
__device__ __forceinline__ void async16(const unsigned short* g,
                                        unsigned short* l) {
  __builtin_amdgcn_global_load_lds(
      (const __attribute__((address_space(1))) unsigned int*)g,
      (__attribute__((address_space(3))) unsigned int*)l, 16, 0, 0);
}

__device__ __forceinline__ float wave_reduce(float v) {
#pragma unroll
  for (int off = 32; off > 0; off >>= 1) v += __shfl_xor(v, off, 64);
  return v;
}

__device__ __forceinline__ float blk_reduce_sum(float v, float* red) {
  v = wave_reduce(v);
  int lane = threadIdx.x & 63, wid = threadIdx.x >> 6;
  __syncthreads();
  if (lane == 0) red[wid] = v;
  __syncthreads();
  return red[0] + red[1] + red[2] + red[3];
}

// blocks [0, N/16): 16 rows of proj -> LN -> ReLU -> xp, s ; pi head.
// blocks [N/16, ..): 32x32 transpose tiles fwTb[c][r] = bf16(f_w[r][c]).
__global__ __launch_bounds__(256) void k_proj(
    const float* __restrict__ x, const float* __restrict__ proj_w,
    const float* __restrict__ proj_b, const float* __restrict__ ln1_g,
    const float* __restrict__ ln1_b, const float* __restrict__ pi_w1,
    const float* __restrict__ pi_b1, const float* __restrict__ pi_w2,
    const float* __restrict__ pi_b2, const float* __restrict__ fw,
    unsigned short* __restrict__ fwTb, float* __restrict__ xp,
    float* __restrict__ s, float* __restrict__ pi, int N, int D) {
  __shared__ float xs[16][68];
  __shared__ float ws[64][20];
  __shared__ float ysh[16][17];
  __shared__ float xps[16][16];
  __shared__ float pr[16][4];
  int tid = threadIdx.x;
  int nProj = N / 16;
  if (blockIdx.x >= (unsigned)nProj) {
    unsigned short(*tile)[33] = (unsigned short(*)[33])&ws[0][0];
    int t = blockIdx.x - nProj;
    int tx = tid & 31, ty = tid >> 5;
    int cols = D / 32;
    int c0 = (t % cols) * 32, r0 = (t / cols) * 32;
#pragma unroll
    for (int i = 0; i < 4; ++i) {
      int r = r0 + ty + i * 8;
      tile[ty + i * 8][tx] = f2bf(fw[(size_t)r * D + c0 + tx]);
    }
    __syncthreads();
#pragma unroll
    for (int i = 0; i < 4; ++i) {
      int cc = c0 + ty + i * 8;
      fwTb[(size_t)cc * D + r0 + tx] = tile[tx][ty + i * 8];
    }
    return;
  }
  int row0 = blockIdx.x * 16;
  int row = tid >> 4, l = tid & 15;
  int lane = tid & 63, w = tid >> 6;
  int skc = (tid & 15) * 4;
  int wk = tid >> 2, wl = (tid & 3) * 4;
  float acc = 0.f;
  for (int k0 = 0; k0 < D; k0 += 64) {
    float4 xv = *(const float4*)(x + (size_t)(row0 + row) * D + k0 + skc);
    float4 wv = *(const float4*)(proj_w + (size_t)(k0 + wk) * 16 + wl);
    __syncthreads();
    *(float4*)&xs[row][skc] = xv;
    *(float4*)&ws[wk][wl] = wv;
    __syncthreads();
#pragma unroll
    for (int kk = 0; kk < 64; kk += 4) {
      float4 a4 = *(const float4*)&xs[row][kk];
      acc += a4.x * ws[kk + 0][l];
      acc += a4.y * ws[kk + 1][l];
      acc += a4.z * ws[kk + 2][l];
      acc += a4.w * ws[kk + 3][l];
    }
  }
  float y = acc + proj_b[l];
  ysh[row][l] = y;
  __syncthreads();
  float mu = 0.f;
#pragma unroll
  for (int t = 0; t < 16; ++t) mu += ysh[row][t];
  mu *= (1.f / 16.f);
  float var = 0.f;
#pragma unroll
  for (int t = 0; t < 16; ++t) { float d2 = ysh[row][t] - mu; var += d2 * d2; }
  var *= (1.f / 16.f);
  float rstd = rsqrtf(var + LN_EPS);
  float xpv = fmaxf((y - mu) * rstd * ln1_g[l] + ln1_b[l], 0.f);
  xps[row][l] = xpv;
  xp[(size_t)(row0 + row) * 16 + l] = xpv;
  float sq = xpv * xpv;
  sq += __shfl_xor(sq, 8, 64);
  sq += __shfl_xor(sq, 4, 64);
  sq += __shfl_xor(sq, 2, 64);
  sq += __shfl_xor(sq, 1, 64);
  if ((lane & 15) == 0) s[row0 + row] = sq;
  __syncthreads();
  float w1r[3][16], b1r[3], w2r[3];
#pragma unroll
  for (int c = 0; c < 3; ++c) {
    int d0 = tid + c * 256;
    b1r[c] = pi_b1[d0];
    w2r[c] = pi_w2[d0];
#pragma unroll
    for (int t = 0; t < 16; ++t) w1r[c][t] = pi_w1[(size_t)t * D + d0];
  }
#pragma unroll
  for (int r = 0; r < 16; ++r) {
    float xv[16];
#pragma unroll
    for (int t4 = 0; t4 < 4; ++t4) {
      float4 xq = *(const float4*)&xps[r][t4 * 4];
      xv[t4 * 4 + 0] = xq.x; xv[t4 * 4 + 1] = xq.y;
      xv[t4 * 4 + 2] = xq.z; xv[t4 * 4 + 3] = xq.w;
    }
    float pa = 0.f;
#pragma unroll
    for (int c = 0; c < 3; ++c) {
      float h = b1r[c];
#pragma unroll
      for (int t = 0; t < 16; ++t) h += xv[t] * w1r[c][t];
      h = fmaxf(h, 0.f);
      pa += h * w2r[c];
    }
    float pv = wave_reduce(pa);
    if (lane == 0) pr[r][w] = pv;
  }
  __syncthreads();
  if (tid < 16) {
    float tot = pr[tid][0] + pr[tid][1] + pr[tid][2] + pr[tid][3] + pi_b2[0];
    pi[row0 + tid] = 1.f / (1.f + expf(-tot));
  }
}

// 4 rows per block, 2 cols per thread; writes Kb bf16, v[i] = pi[i]/rowsum.
__global__ __launch_bounds__(256) void k_keps(
    const float* __restrict__ xp, const float* __restrict__ s,
    const float* __restrict__ pi, unsigned short* __restrict__ Kb,
    float* __restrict__ v, int N) {
  __shared__ float qs[4][4];
  int i0 = blockIdx.x * 4;
  int tid = threadIdx.x, lane = tid & 63, w = tid >> 6;
  float a[4][16], si[4];
#pragma unroll
  for (int r = 0; r < 4; ++r) {
    const float* ap = xp + (size_t)(i0 + r) * 16;
#pragma unroll
    for (int t = 0; t < 16; ++t) a[r][t] = ap[t];
    si[r] = s[i0 + r];
  }
  const float c = 1.f / (4.f * EPSILON);
  float qa[4] = {0.f, 0.f, 0.f, 0.f};
  for (int it = 0; it < N / 512; ++it) {
    int j = it * 512 + tid * 2;
    const float4* bp = (const float4*)(xp + (size_t)j * 16);
    float4 b0 = bp[0], b1 = bp[1], b2 = bp[2], b3 = bp[3];
    float4 c0 = bp[4], c1 = bp[5], c2 = bp[6], c3 = bp[7];
    float bv[16] = {b0.x, b0.y, b0.z, b0.w, b1.x, b1.y, b1.z, b1.w,
                    b2.x, b2.y, b2.z, b2.w, b3.x, b3.y, b3.z, b3.w};
    float cv[16] = {c0.x, c0.y, c0.z, c0.w, c1.x, c1.y, c1.z, c1.w,
                    c2.x, c2.y, c2.z, c2.w, c3.x, c3.y, c3.z, c3.w};
    float sj0 = s[j], sj1 = s[j + 1];
#pragma unroll
    for (int r = 0; r < 4; ++r) {
      float d0 = 0.f, d1 = 0.f;
#pragma unroll
      for (int t = 0; t < 16; ++t) { d0 += a[r][t] * bv[t]; d1 += a[r][t] * cv[t]; }
      float k0 = __expf(-c * (si[r] + sj0 - 2.f * d0));
      float k1 = __expf(-c * (si[r] + sj1 - 2.f * d1));
      *(unsigned int*)(Kb + (size_t)(i0 + r) * N + j) = pack2(k0, k1);
      qa[r] += k0 + k1;
    }
  }
#pragma unroll
  for (int r = 0; r < 4; ++r) {
    float t = wave_reduce(qa[r]);
    if (lane == 0) qs[r][w] = t;
  }
  __syncthreads();
  if (tid < 4) {
    float tot = qs[tid][0] + qs[tid][1] + qs[tid][2] + qs[tid][3];
    v[i0 + tid] = pi[i0 + tid] / tot;
  }
}

// blocks [0, N): dv[i] = sum_j bf16(Kb[i][j])*v[j] + 1e-5
// blocks [N, ..): xvbT[d][j] = bf16(v[j] * x[j][d]) (32x32 transpose tiles)
__global__ __launch_bounds__(256) void k_prep(
    const unsigned short* __restrict__ Kb, const float* __restrict__ v,
    float* __restrict__ dv, const float* __restrict__ x,
    unsigned short* __restrict__ xvbT, int N, int D) {
  __shared__ float sh[544];
  int bid = blockIdx.x, tid = threadIdx.x;
  if (bid < N) {
    int i = bid;
    float acc = 0.f;
    for (int j8 = tid * 8; j8 < N; j8 += 256 * 8) {
      uint4 kv4 = *(const uint4*)(Kb + (size_t)i * N + j8);
      float4 va = *(const float4*)(v + j8);
      float4 vb = *(const float4*)(v + j8 + 4);
      unsigned int u;
      u = kv4.x;
      acc += __uint_as_float(u << 16) * va.x + __uint_as_float(u & 0xffff0000u) * va.y;
      u = kv4.y;
      acc += __uint_as_float(u << 16) * va.z + __uint_as_float(u & 0xffff0000u) * va.w;
      u = kv4.z;
      acc += __uint_as_float(u << 16) * vb.x + __uint_as_float(u & 0xffff0000u) * vb.y;
      u = kv4.w;
      acc += __uint_as_float(u << 16) * vb.z + __uint_as_float(u & 0xffff0000u) * vb.w;
    }
    float tot = blk_reduce_sum(acc, sh);
    if (tid == 0) dv[i] = tot + 1e-5f;
  } else {
    int t = bid - N;
    unsigned short(*tile)[33] = (unsigned short(*)[33])sh;
    int tx = tid & 31, ty = tid >> 5;
    int cols = D / 32;
    int c0 = (t % cols) * 32;  // over D
    int r0 = (t / cols) * 32;  // over N
#pragma unroll
    for (int i = 0; i < 4; ++i) {
      int r = r0 + ty + i * 8;
      tile[ty + i * 8][tx] = f2bf(v[r] * x[(size_t)r * D + c0 + tx]);
    }
    __syncthreads();
#pragma unroll
    for (int i = 0; i < 4; ++i) {
      int cc = c0 + ty + i * 8;
      xvbT[(size_t)cc * N + r0 + tx] = tile[tx][ty + i * 8];
    }
  }
}

// Async-staged 64x64 K-loop, BK=128, XOR-swizzled unpadded LDS.
#define GEMM_KLOOP(Aptr, Bptr, Kdim)                                          \
  int tid = threadIdx.x;                                                      \
  int w = tid >> 6, l = tid & 63;                                             \
  int ln = l & 15, quad = l >> 4;                                             \
  int mh = (w & 1) * 32, nh = (w >> 1) * 32;                                  \
  int row0 = blockIdx.y * 64, col0 = blockIdx.x * 64;                         \
  int srow = w * 4 + (l >> 4);                                                \
  int swz = ((l & 15) ^ srow) * 8;                                            \
  const unsigned short* gA = Aptr + (size_t)(row0 + srow) * Kdim + swz;       \
  const unsigned short* gB = Bptr + (size_t)(col0 + srow) * Kdim + swz;       \
  f32x4 acc[2][2] = {};                                                       \
  for (int k0 = 0; k0 < Kdim; k0 += 128) {                                    \
    __syncthreads();                                                          \
    _Pragma("unroll")                                                         \
    for (int q = 0; q < 4; ++q) {                                             \
      async16(gA + (size_t)q * 16 * Kdim + k0, As + (q * 16 + w * 4) * 128);  \
      async16(gB + (size_t)q * 16 * Kdim + k0, Bs + (q * 16 + w * 4) * 128);  \
    }                                                                         \
    __syncthreads();                                                          \
    _Pragma("unroll")                                                         \
    for (int ks = 0; ks < 4; ++ks) {                                          \
      bf16x8 bfr[2], afr[2];                                                  \
      _Pragma("unroll")                                                       \
      for (int nt = 0; nt < 2; ++nt) {                                        \
        int r = nh + nt * 16 + ln;                                            \
        int cix = (ks * 4 + quad) ^ (r & 15);                                 \
        bfr[nt] = *(const bf16x8*)&Bs[r * 128 + cix * 8];                     \
      }                                                                       \
      _Pragma("unroll")                                                       \
      for (int mt = 0; mt < 2; ++mt) {                                        \
        int r = mh + mt * 16 + ln;                                            \
        int cix = (ks * 4 + quad) ^ (r & 15);                                 \
        afr[mt] = *(const bf16x8*)&As[r * 128 + cix * 8];                     \
      }                                                                       \
      _Pragma("unroll")                                                       \
      for (int mt = 0; mt < 2; ++mt)                                          \
        _Pragma("unroll")                                                     \
        for (int nt = 0; nt < 2; ++nt)                                        \
          acc[mt][nt] = __builtin_amdgcn_mfma_f32_16x16x32_bf16(              \
              afr[mt], bfr[nt], acc[mt][nt], 0, 0, 0);                        \
    }                                                                         \
  }

// Y = Kb @ xvbT^T; Z[row][col] = bf16(c2*x[row][col] + (c3/dv[row])*acc)
__global__ __launch_bounds__(256) void k_gemmA(
    const unsigned short* __restrict__ A, const unsigned short* __restrict__ Bt,
    const float* __restrict__ x, const float* __restrict__ dv,
    const float* __restrict__ dtp, unsigned short* __restrict__ Z,
    int M, int N, int K) {
  __shared__ unsigned short As[64 * 128];
  __shared__ unsigned short Bs[64 * 128];
  GEMM_KLOOP(A, Bt, K)
  float dtv = dtp[0];
  float c2 = (1.f - ALPHA) * (1.f - 2.f * dtv);
  float c3b = (1.f - ALPHA) * 2.f * dtv / EPSILON;
#pragma unroll
  for (int mt = 0; mt < 2; ++mt)
#pragma unroll
    for (int nt = 0; nt < 2; ++nt) {
      int col = col0 + nh + nt * 16 + ln;
#pragma unroll
      for (int r = 0; r < 4; ++r) {
        int row = row0 + mh + mt * 16 + quad * 4 + r;
        float c3 = c3b / dv[row];
        Z[(size_t)row * N + col] =
            f2bf(c2 * x[(size_t)row * N + col] + c3 * acc[mt][nt][r]);
      }
    }
}

// pre = ALPHA*x + Z @ fwTb^T + cb*bias -> out; the last block of each 64-row
// band (completion counter) then LayerNorms those rows in place.
__global__ __launch_bounds__(256) void k_gemmB_ln(
    const unsigned short* __restrict__ A, const unsigned short* __restrict__ Bt,
    const float* __restrict__ x, const float* __restrict__ bias,
    const float* __restrict__ dtp, const float* __restrict__ g,
    const float* __restrict__ b, unsigned* __restrict__ cnt,
    float* __restrict__ out, int M, int N, int K) {
  __shared__ unsigned short As[64 * 128];
  __shared__ unsigned short Bs[64 * 128];
  __shared__ unsigned done;
  GEMM_KLOOP(A, Bt, K)
  float dtv = dtp[0];
  float cb = (1.f - ALPHA) * (1.f - 2.f * dtv) +
             (1.f - ALPHA) * 2.f * dtv / EPSILON;
#pragma unroll
  for (int mt = 0; mt < 2; ++mt)
#pragma unroll
    for (int nt = 0; nt < 2; ++nt) {
      int col = col0 + nh + nt * 16 + ln;
      float bv = cb * bias[col];
#pragma unroll
      for (int r = 0; r < 4; ++r) {
        int row = row0 + mh + mt * 16 + quad * 4 + r;
        size_t idx = (size_t)row * N + col;
        out[idx] = ALPHA * x[idx] + acc[mt][nt][r] + bv;
      }
    }
  // completion counter: last col-tile block of this row band does the LN
  __threadfence();  // release our tile stores to device scope
  if (tid == 0) done = atomicAdd(cnt + blockIdx.y, 1u);
  __syncthreads();
  if (done != gridDim.x - 1) return;
  __threadfence();  // acquire other blocks' stores
  int lane = tid & 63;
  for (int r = w; r < 64; r += 4) {  // wave w handles rows w, w+4, ...
    float* rowp = out + (size_t)(row0 + r) * N;
    float4 a = ((const float4*)rowp)[lane];
    float4 bq = ((const float4*)rowp)[lane + 64];
    float4 cq = ((const float4*)rowp)[lane + 128];
    float sum = a.x + a.y + a.z + a.w + bq.x + bq.y + bq.z + bq.w +
                cq.x + cq.y + cq.z + cq.w;
    float mu = wave_reduce(sum) * (1.f / 768.f);
    float sq = (a.x - mu) * (a.x - mu) + (a.y - mu) * (a.y - mu) +
               (a.z - mu) * (a.z - mu) + (a.w - mu) * (a.w - mu) +
               (bq.x - mu) * (bq.x - mu) + (bq.y - mu) * (bq.y - mu) +
               (bq.z - mu) * (bq.z - mu) + (bq.w - mu) * (bq.w - mu) +
               (cq.x - mu) * (cq.x - mu) + (cq.y - mu) * (cq.y - mu) +
               (cq.z - mu) * (cq.z - mu) + (cq.w - mu) * (cq.w - mu);
    float var = wave_reduce(sq) * (1.f / 768.f);
    float rs = rsqrtf(var + LN_EPS);
    float4 g0 = ((const float4*)g)[lane], g1 = ((const float4*)g)[lane + 64],
           g2 = ((const float4*)g)[lane + 128];
    float4 b0 = ((const float4*)b)[lane], b1 = ((const float4*)b)[lane + 64],
           b2 = ((const float4*)b)[lane + 128];
    float4 o0, o1, o2;
    o0.x = (a.x - mu) * rs * g0.x + b0.x;
    o0.y = (a.y - mu) * rs * g0.y + b0.y;
    o0.z = (a.z - mu) * rs * g0.z + b0.z;
    o0.w = (a.w - mu) * rs * g0.w + b0.w;
    o1.x = (bq.x - mu) * rs * g1.x + b1.x;
    o1.y = (bq.y - mu) * rs * g1.y + b1.y;
    o1.z = (bq.z - mu) * rs * g1.z + b1.z;
    o1.w = (bq.w - mu) * rs * g1.w + b1.w;
    o2.x = (cq.x - mu) * rs * g2.x + b2.x;
    o2.y = (cq.y - mu) * rs * g2.y + b2.y;
    o2.z = (cq.z - mu) * rs * g2.z + b2.z;
    o2.w = (cq.w - mu) * rs * g2.w + b2.w;
    ((float4*)rowp)[lane] = o0;
    ((float4*)rowp)[lane + 64] = o1;
    ((float4*)rowp)[lane + 128] = o2;
  }
}

extern "C" void kernel_launch(void* const* d_in, const int* in_sizes, int n_in,
                              void* d_out, int out_size, void* d_ws, size_t ws_size,
                              hipStream_t stream) {
  const float* x = (const float*)d_in[0];
  const float* proj_w = (const float*)d_in[1];
  const float* proj_b = (const float*)d_in[2];
  const float* ln1_g = (const float*)d_in[3];
  const float* ln1_b = (const float*)d_in[4];
  const float* pi_w1 = (const float*)d_in[5];
  const float* pi_b1 = (const float*)d_in[6];
  const float* pi_w2 = (const float*)d_in[7];
  const float* pi_b2 = (const float*)d_in[8];
  const float* dt = (const float*)d_in[9];
  const float* f_w = (const float*)d_in[10];
  const float* f_b = (const float*)d_in[11];
  const float* ln2_g = (const float*)d_in[12];
  const float* ln2_b = (const float*)d_in[13];
  float* out = (float*)d_out;

  int D = in_sizes[11];      // 768
  int N = in_sizes[0] / D;   // 2048

  unsigned short* Kb = (unsigned short*)d_ws;                   // N*N bf16
  unsigned short* xvbT = Kb + (size_t)N * N;                    // D*N bf16
  unsigned short* fwTb = xvbT + (size_t)D * N;                  // D*D bf16
  unsigned short* Z = fwTb + (size_t)D * D;                     // N*D bf16
  float* xp = (float*)(Z + (size_t)N * D);                      // N*16
  float* s = xp + (size_t)N * 16;                               // N
  float* pi = s + N;                                            // N
  float* v = pi + N;                                            // N
  float* dv = v + N;                                            // N
  unsigned* cnt = (unsigned*)(dv + N);                          // N/64 counters

  int fwB = (D / 32) * (D / 32);
  int xvtB = (D / 32) * (N / 32);

  hipMemsetAsync(cnt, 0, (N / 64) * sizeof(unsigned), stream);
  k_proj<<<N / 16 + fwB, 256, 0, stream>>>(x, proj_w, proj_b, ln1_g, ln1_b,
                                           pi_w1, pi_b1, pi_w2, pi_b2, f_w,
                                           fwTb, xp, s, pi, N, D);
  k_keps<<<N / 4, 256, 0, stream>>>(xp, s, pi, Kb, v, N);
  k_prep<<<N + xvtB, 256, 0, stream>>>(Kb, v, dv, x, xvbT, N, D);
  k_gemmA<<<dim3(D / 64, N / 64), 256, 0, stream>>>(Kb, xvbT, x, dv, dt, Z,
                                                    N, D, N);
  k_gemmB_ln<<<dim3(D / 64, N / 64), 256, 0, stream>>>(
      Z, fwTb, x, f_b, dt, ln2_g, ln2_b, cnt, out, N, D, D);
}

// Round 12
// 157.482 us; speedup vs baseline: 1.4320x; 1.4320x over previous
//
#include <hip/hip_runtime.h>
#include <math.h>

#define EPSILON 0.3f
#define ALPHA 0.7f
#define LN_EPS 1e-5f

typedef __bf16 bf16x8 __attribute__((ext_vector_type(8)));
typedef float f32x4 __attribute__((ext_vector_type(4)));

__device__ __forceinline__ unsigned short f2bf(float f) {
  unsigned int u = __float_as_uint(f);
  return (unsigned short)((u + 0x7fffu + ((u >> 16) & 1u)) >> 16);
}
__device__ __forceinline__ unsigned int pack2(float lo, float hi) {
  return (unsigned int)f2bf(lo) | ((unsigned int)f2bf(hi) << 16);
}

// async 16B/lane global->LDS DMA; lds base wave-uniform (HW adds lane*16)
__device__ __forceinline__ void async16(const unsigned short* g,
                                        unsigned short* l) {
  __builtin_amdgcn_global_load_lds(
      (const __attribute__((address_space(1))) unsigned int*)g,
      (__attribute__((address_space(3))) unsigned int*)l, 16, 0, 0);
}

__device__ __forceinline__ float wave_reduce(float v) {
#pragma unroll
  for (int off = 32; off > 0; off >>= 1) v += __shfl_xor(v, off, 64);
  return v;
}

__device__ __forceinline__ float blk_reduce_sum(float v, float* red) {
  v = wave_reduce(v);
  int lane = threadIdx.x & 63, wid = threadIdx.x >> 6;
  __syncthreads();
  if (lane == 0) red[wid] = v;
  __syncthreads();
  return red[0] + red[1] + red[2] + red[3];
}

// blocks [0, N/16): 16 rows of proj -> LN -> ReLU -> xp, s ; pi head.
// blocks [N/16, ..): 32x32 transpose tiles fwTb[c][r] = bf16(f_w[r][c]).
__global__ __launch_bounds__(256) void k_proj(
    const float* __restrict__ x, const float* __restrict__ proj_w,
    const float* __restrict__ proj_b, const float* __restrict__ ln1_g,
    const float* __restrict__ ln1_b, const float* __restrict__ pi_w1,
    const float* __restrict__ pi_b1, const float* __restrict__ pi_w2,
    const float* __restrict__ pi_b2, const float* __restrict__ fw,
    unsigned short* __restrict__ fwTb, float* __restrict__ xp,
    float* __restrict__ s, float* __restrict__ pi, int N, int D) {
  __shared__ float xs[16][68];
  __shared__ float ws[64][20];
  __shared__ float ysh[16][17];
  __shared__ float xps[16][16];
  __shared__ float pr[16][4];
  int tid = threadIdx.x;
  int nProj = N / 16;
  if (blockIdx.x >= (unsigned)nProj) {
    unsigned short(*tile)[33] = (unsigned short(*)[33])&ws[0][0];
    int t = blockIdx.x - nProj;
    int tx = tid & 31, ty = tid >> 5;
    int cols = D / 32;
    int c0 = (t % cols) * 32, r0 = (t / cols) * 32;
#pragma unroll
    for (int i = 0; i < 4; ++i) {
      int r = r0 + ty + i * 8;
      tile[ty + i * 8][tx] = f2bf(fw[(size_t)r * D + c0 + tx]);
    }
    __syncthreads();
#pragma unroll
    for (int i = 0; i < 4; ++i) {
      int cc = c0 + ty + i * 8;
      fwTb[(size_t)cc * D + r0 + tx] = tile[tx][ty + i * 8];
    }
    return;
  }
  int row0 = blockIdx.x * 16;
  int row = tid >> 4, l = tid & 15;
  int lane = tid & 63, w = tid >> 6;
  int skc = (tid & 15) * 4;
  int wk = tid >> 2, wl = (tid & 3) * 4;
  float acc = 0.f;
  for (int k0 = 0; k0 < D; k0 += 64) {
    float4 xv = *(const float4*)(x + (size_t)(row0 + row) * D + k0 + skc);
    float4 wv = *(const float4*)(proj_w + (size_t)(k0 + wk) * 16 + wl);
    __syncthreads();
    *(float4*)&xs[row][skc] = xv;
    *(float4*)&ws[wk][wl] = wv;
    __syncthreads();
#pragma unroll
    for (int kk = 0; kk < 64; kk += 4) {
      float4 a4 = *(const float4*)&xs[row][kk];
      acc += a4.x * ws[kk + 0][l];
      acc += a4.y * ws[kk + 1][l];
      acc += a4.z * ws[kk + 2][l];
      acc += a4.w * ws[kk + 3][l];
    }
  }
  float y = acc + proj_b[l];
  ysh[row][l] = y;
  __syncthreads();
  float mu = 0.f;
#pragma unroll
  for (int t = 0; t < 16; ++t) mu += ysh[row][t];
  mu *= (1.f / 16.f);
  float var = 0.f;
#pragma unroll
  for (int t = 0; t < 16; ++t) { float d2 = ysh[row][t] - mu; var += d2 * d2; }
  var *= (1.f / 16.f);
  float rstd = rsqrtf(var + LN_EPS);
  float xpv = fmaxf((y - mu) * rstd * ln1_g[l] + ln1_b[l], 0.f);
  xps[row][l] = xpv;
  xp[(size_t)(row0 + row) * 16 + l] = xpv;
  float sq = xpv * xpv;
  sq += __shfl_xor(sq, 8, 64);
  sq += __shfl_xor(sq, 4, 64);
  sq += __shfl_xor(sq, 2, 64);
  sq += __shfl_xor(sq, 1, 64);
  if ((lane & 15) == 0) s[row0 + row] = sq;
  __syncthreads();
  float w1r[3][16], b1r[3], w2r[3];
#pragma unroll
  for (int c = 0; c < 3; ++c) {
    int d0 = tid + c * 256;
    b1r[c] = pi_b1[d0];
    w2r[c] = pi_w2[d0];
#pragma unroll
    for (int t = 0; t < 16; ++t) w1r[c][t] = pi_w1[(size_t)t * D + d0];
  }
#pragma unroll
  for (int r = 0; r < 16; ++r) {
    float xv[16];
#pragma unroll
    for (int t4 = 0; t4 < 4; ++t4) {
      float4 xq = *(const float4*)&xps[r][t4 * 4];
      xv[t4 * 4 + 0] = xq.x; xv[t4 * 4 + 1] = xq.y;
      xv[t4 * 4 + 2] = xq.z; xv[t4 * 4 + 3] = xq.w;
    }
    float pa = 0.f;
#pragma unroll
    for (int c = 0; c < 3; ++c) {
      float h = b1r[c];
#pragma unroll
      for (int t = 0; t < 16; ++t) h += xv[t] * w1r[c][t];
      h = fmaxf(h, 0.f);
      pa += h * w2r[c];
    }
    float pv = wave_reduce(pa);
    if (lane == 0) pr[r][w] = pv;
  }
  __syncthreads();
  if (tid < 16) {
    float tot = pr[tid][0] + pr[tid][1] + pr[tid][2] + pr[tid][3] + pi_b2[0];
    pi[row0 + tid] = 1.f / (1.f + expf(-tot));
  }
}

// 4 rows per block, 2 cols per thread; writes Kb bf16, v[i] = pi[i]/rowsum.
__global__ __launch_bounds__(256) void k_keps(
    const float* __restrict__ xp, const float* __restrict__ s,
    const float* __restrict__ pi, unsigned short* __restrict__ Kb,
    float* __restrict__ v, int N) {
  __shared__ float qs[4][4];
  int i0 = blockIdx.x * 4;
  int tid = threadIdx.x, lane = tid & 63, w = tid >> 6;
  float a[4][16], si[4];
#pragma unroll
  for (int r = 0; r < 4; ++r) {
    const float* ap = xp + (size_t)(i0 + r) * 16;
#pragma unroll
    for (int t = 0; t < 16; ++t) a[r][t] = ap[t];
    si[r] = s[i0 + r];
  }
  const float c = 1.f / (4.f * EPSILON);
  float qa[4] = {0.f, 0.f, 0.f, 0.f};
  for (int it = 0; it < N / 512; ++it) {
    int j = it * 512 + tid * 2;
    const float4* bp = (const float4*)(xp + (size_t)j * 16);
    float4 b0 = bp[0], b1 = bp[1], b2 = bp[2], b3 = bp[3];
    float4 c0 = bp[4], c1 = bp[5], c2 = bp[6], c3 = bp[7];
    float bv[16] = {b0.x, b0.y, b0.z, b0.w, b1.x, b1.y, b1.z, b1.w,
                    b2.x, b2.y, b2.z, b2.w, b3.x, b3.y, b3.z, b3.w};
    float cv[16] = {c0.x, c0.y, c0.z, c0.w, c1.x, c1.y, c1.z, c1.w,
                    c2.x, c2.y, c2.z, c2.w, c3.x, c3.y, c3.z, c3.w};
    float sj0 = s[j], sj1 = s[j + 1];
#pragma unroll
    for (int r = 0; r < 4; ++r) {
      float d0 = 0.f, d1 = 0.f;
#pragma unroll
      for (int t = 0; t < 16; ++t) { d0 += a[r][t] * bv[t]; d1 += a[r][t] * cv[t]; }
      float k0 = __expf(-c * (si[r] + sj0 - 2.f * d0));
      float k1 = __expf(-c * (si[r] + sj1 - 2.f * d1));
      *(unsigned int*)(Kb + (size_t)(i0 + r) * N + j) = pack2(k0, k1);
      qa[r] += k0 + k1;
    }
  }
#pragma unroll
  for (int r = 0; r < 4; ++r) {
    float t = wave_reduce(qa[r]);
    if (lane == 0) qs[r][w] = t;
  }
  __syncthreads();
  if (tid < 4) {
    float tot = qs[tid][0] + qs[tid][1] + qs[tid][2] + qs[tid][3];
    v[i0 + tid] = pi[i0 + tid] / tot;
  }
}

// blocks [0, N): dv[i] = sum_j bf16(Kb[i][j])*v[j] + 1e-5
// blocks [N, ..): xvbT[d][j] = bf16(v[j] * x[j][d]) (32x32 transpose tiles)
__global__ __launch_bounds__(256) void k_prep(
    const unsigned short* __restrict__ Kb, const float* __restrict__ v,
    float* __restrict__ dv, const float* __restrict__ x,
    unsigned short* __restrict__ xvbT, int N, int D) {
  __shared__ float sh[544];
  int bid = blockIdx.x, tid = threadIdx.x;
  if (bid < N) {
    int i = bid;
    float acc = 0.f;
    for (int j8 = tid * 8; j8 < N; j8 += 256 * 8) {
      uint4 kv4 = *(const uint4*)(Kb + (size_t)i * N + j8);
      float4 va = *(const float4*)(v + j8);
      float4 vb = *(const float4*)(v + j8 + 4);
      unsigned int u;
      u = kv4.x;
      acc += __uint_as_float(u << 16) * va.x + __uint_as_float(u & 0xffff0000u) * va.y;
      u = kv4.y;
      acc += __uint_as_float(u << 16) * va.z + __uint_as_float(u & 0xffff0000u) * va.w;
      u = kv4.z;
      acc += __uint_as_float(u << 16) * vb.x + __uint_as_float(u & 0xffff0000u) * vb.y;
      u = kv4.w;
      acc += __uint_as_float(u << 16) * vb.z + __uint_as_float(u & 0xffff0000u) * vb.w;
    }
    float tot = blk_reduce_sum(acc, sh);
    if (tid == 0) dv[i] = tot + 1e-5f;
  } else {
    int t = bid - N;
    unsigned short(*tile)[33] = (unsigned short(*)[33])sh;
    int tx = tid & 31, ty = tid >> 5;
    int cols = D / 32;
    int c0 = (t % cols) * 32;  // over D
    int r0 = (t / cols) * 32;  // over N
#pragma unroll
    for (int i = 0; i < 4; ++i) {
      int r = r0 + ty + i * 8;
      tile[ty + i * 8][tx] = f2bf(v[r] * x[(size_t)r * D + c0 + tx]);
    }
    __syncthreads();
#pragma unroll
    for (int i = 0; i < 4; ++i) {
      int cc = c0 + ty + i * 8;
      xvbT[(size_t)cc * N + r0 + tx] = tile[tx][ty + i * 8];
    }
  }
}

// Async-staged 64x64 K-loop, BK=128, XOR-swizzled unpadded LDS.
// Stage: LDS[r][c] = G[r][c ^ (r&15)] (chunks of 8 bf16). Per wave: 4 async16
// per matrix covering rows {q*16 + w*4 + (l>>4)}. Read chunk (ks*4+quad)^(r&15)
// -> max 2-way bank aliasing (free, m136).
#define GEMM_KLOOP(Aptr, Bptr, Kdim)                                          \
  int tid = threadIdx.x;                                                      \
  int w = tid >> 6, l = tid & 63;                                             \
  int ln = l & 15, quad = l >> 4;                                             \
  int mh = (w & 1) * 32, nh = (w >> 1) * 32;                                  \
  int row0 = blockIdx.y * 64, col0 = blockIdx.x * 64;                         \
  int srow = w * 4 + (l >> 4);                                                \
  int swz = ((l & 15) ^ srow) * 8;                                            \
  const unsigned short* gA = Aptr + (size_t)(row0 + srow) * Kdim + swz;       \
  const unsigned short* gB = Bptr + (size_t)(col0 + srow) * Kdim + swz;       \
  f32x4 acc[2][2] = {};                                                       \
  for (int k0 = 0; k0 < Kdim; k0 += 128) {                                    \
    __syncthreads();                                                          \
    _Pragma("unroll")                                                         \
    for (int q = 0; q < 4; ++q) {                                             \
      async16(gA + (size_t)q * 16 * Kdim + k0, As + (q * 16 + w * 4) * 128);  \
      async16(gB + (size_t)q * 16 * Kdim + k0, Bs + (q * 16 + w * 4) * 128);  \
    }                                                                         \
    __syncthreads();                                                          \
    _Pragma("unroll")                                                         \
    for (int ks = 0; ks < 4; ++ks) {                                          \
      bf16x8 bfr[2], afr[2];                                                  \
      _Pragma("unroll")                                                       \
      for (int nt = 0; nt < 2; ++nt) {                                        \
        int r = nh + nt * 16 + ln;                                            \
        int cix = (ks * 4 + quad) ^ (r & 15);                                 \
        bfr[nt] = *(const bf16x8*)&Bs[r * 128 + cix * 8];                     \
      }                                                                       \
      _Pragma("unroll")                                                       \
      for (int mt = 0; mt < 2; ++mt) {                                        \
        int r = mh + mt * 16 + ln;                                            \
        int cix = (ks * 4 + quad) ^ (r & 15);                                 \
        afr[mt] = *(const bf16x8*)&As[r * 128 + cix * 8];                     \
      }                                                                       \
      _Pragma("unroll")                                                       \
      for (int mt = 0; mt < 2; ++mt)                                          \
        _Pragma("unroll")                                                     \
        for (int nt = 0; nt < 2; ++nt)                                        \
          acc[mt][nt] = __builtin_amdgcn_mfma_f32_16x16x32_bf16(              \
              afr[mt], bfr[nt], acc[mt][nt], 0, 0, 0);                        \
    }                                                                         \
  }

// Y = Kb @ xvbT^T; Z[row][col] = bf16(c2*x[row][col] + (c3/dv[row])*acc)
__global__ __launch_bounds__(256) void k_gemmA(
    const unsigned short* __restrict__ A, const unsigned short* __restrict__ Bt,
    const float* __restrict__ x, const float* __restrict__ dv,
    const float* __restrict__ dtp, unsigned short* __restrict__ Z,
    int M, int N, int K) {
  __shared__ unsigned short As[64 * 128];
  __shared__ unsigned short Bs[64 * 128];
  GEMM_KLOOP(A, Bt, K)
  float dtv = dtp[0];
  float c2 = (1.f - ALPHA) * (1.f - 2.f * dtv);
  float c3b = (1.f - ALPHA) * 2.f * dtv / EPSILON;
#pragma unroll
  for (int mt = 0; mt < 2; ++mt)
#pragma unroll
    for (int nt = 0; nt < 2; ++nt) {
      int col = col0 + nh + nt * 16 + ln;
#pragma unroll
      for (int r = 0; r < 4; ++r) {
        int row = row0 + mh + mt * 16 + quad * 4 + r;
        float c3 = c3b / dv[row];
        Z[(size_t)row * N + col] =
            f2bf(c2 * x[(size_t)row * N + col] + c3 * acc[mt][nt][r]);
      }
    }
}

// pre = ALPHA*x + Z @ fwTb^T + cb*bias; writes fp32 out
__global__ __launch_bounds__(256) void k_gemmB(
    const unsigned short* __restrict__ A, const unsigned short* __restrict__ Bt,
    const float* __restrict__ x, const float* __restrict__ bias,
    const float* __restrict__ dtp, float* __restrict__ out,
    int M, int N, int K) {
  __shared__ unsigned short As[64 * 128];
  __shared__ unsigned short Bs[64 * 128];
  GEMM_KLOOP(A, Bt, K)
  float dtv = dtp[0];
  float cb = (1.f - ALPHA) * (1.f - 2.f * dtv) +
             (1.f - ALPHA) * 2.f * dtv / EPSILON;
#pragma unroll
  for (int mt = 0; mt < 2; ++mt)
#pragma unroll
    for (int nt = 0; nt < 2; ++nt) {
      int col = col0 + nh + nt * 16 + ln;
      float bv = cb * bias[col];
#pragma unroll
      for (int r = 0; r < 4; ++r) {
        int row = row0 + mh + mt * 16 + quad * 4 + r;
        size_t idx = (size_t)row * N + col;
        out[idx] = ALPHA * x[idx] + acc[mt][nt][r] + bv;
      }
    }
}

// In-place LayerNorm over rows of out (D elements, D/256 <= 4)
__global__ __launch_bounds__(256) void k_ln_rows(
    float* __restrict__ out, const float* __restrict__ g,
    const float* __restrict__ b, int D) {
  __shared__ float red[4];
  int i = blockIdx.x, tid = threadIdx.x;
  float vv[4];
  int nt = D / 256;
  float sum = 0.f;
  for (int t = 0; t < nt; ++t) {
    vv[t] = out[(size_t)i * D + tid + t * 256];
    sum += vv[t];
  }
  float mu = blk_reduce_sum(sum, red) / (float)D;
  float sq = 0.f;
  for (int t = 0; t < nt; ++t) { float d2 = vv[t] - mu; sq += d2 * d2; }
  float var = blk_reduce_sum(sq, red) / (float)D;
  float rs = rsqrtf(var + LN_EPS);
  for (int t = 0; t < nt; ++t) {
    int d0 = tid + t * 256;
    out[(size_t)i * D + d0] = (vv[t] - mu) * rs * g[d0] + b[d0];
  }
}

extern "C" void kernel_launch(void* const* d_in, const int* in_sizes, int n_in,
                              void* d_out, int out_size, void* d_ws, size_t ws_size,
                              hipStream_t stream) {
  const float* x = (const float*)d_in[0];
  const float* proj_w = (const float*)d_in[1];
  const float* proj_b = (const float*)d_in[2];
  const float* ln1_g = (const float*)d_in[3];
  const float* ln1_b = (const float*)d_in[4];
  const float* pi_w1 = (const float*)d_in[5];
  const float* pi_b1 = (const float*)d_in[6];
  const float* pi_w2 = (const float*)d_in[7];
  const float* pi_b2 = (const float*)d_in[8];
  const float* dt = (const float*)d_in[9];
  const float* f_w = (const float*)d_in[10];
  const float* f_b = (const float*)d_in[11];
  const float* ln2_g = (const float*)d_in[12];
  const float* ln2_b = (const float*)d_in[13];
  float* out = (float*)d_out;

  int D = in_sizes[11];      // 768
  int N = in_sizes[0] / D;   // 2048

  unsigned short* Kb = (unsigned short*)d_ws;                   // N*N bf16
  unsigned short* xvbT = Kb + (size_t)N * N;                    // D*N bf16
  unsigned short* fwTb = xvbT + (size_t)D * N;                  // D*D bf16
  unsigned short* Z = fwTb + (size_t)D * D;                     // N*D bf16
  float* xp = (float*)(Z + (size_t)N * D);                      // N*16
  float* s = xp + (size_t)N * 16;                               // N
  float* pi = s + N;                                            // N
  float* v = pi + N;                                            // N
  float* dv = v + N;                                            // N

  int fwB = (D / 32) * (D / 32);
  int xvtB = (D / 32) * (N / 32);

  k_proj<<<N / 16 + fwB, 256, 0, stream>>>(x, proj_w, proj_b, ln1_g, ln1_b,
                                           pi_w1, pi_b1, pi_w2, pi_b2, f_w,
                                           fwTb, xp, s, pi, N, D);
  k_keps<<<N / 4, 256, 0, stream>>>(xp, s, pi, Kb, v, N);
  k_prep<<<N + xvtB, 256, 0, stream>>>(Kb, v, dv, x, xvbT, N, D);
  k_gemmA<<<dim3(D / 64, N / 64), 256, 0, stream>>>(Kb, xvbT, x, dv, dt, Z,
                                                    N, D, N);
  k_gemmB<<<dim3(D / 64, N / 64), 256, 0, stream>>>(Z, fwTb, x, f_b, dt, out,
                                                    N, D, D);
  k_ln_rows<<<N, 256, 0, stream>>>(out, ln2_g, ln2_b, D);
}